// Round 15
// baseline (700.259 us; speedup 1.0000x reference)
//
#include <hip/hip_runtime.h>

#define D 256
#define SB 1024
typedef __attribute__((ext_vector_type(8))) short short8;
typedef __attribute__((ext_vector_type(4))) float floatx4;

__device__ __forceinline__ unsigned short f2bf(float f) {
  unsigned int u = __float_as_uint(f);
  u = (u + 0x7FFF + ((u >> 16) & 1)) >> 16;   // RNE
  return (unsigned short)u;
}
__device__ __forceinline__ float bf2f(unsigned short h) {
  return __uint_as_float(((unsigned int)h) << 16);
}

// ---------------- fused independent setup: zero | bounds | cvt | cvt_w x2 --
__global__ __launch_bounds__(256) void k_setup(
    int* __restrict__ cur, int RN,
    const int* __restrict__ batch, int* __restrict__ gstart, int N, int G,
    const float* __restrict__ table, unsigned short* __restrict__ tableb, int TN,
    const float* __restrict__ root1, const float* __restrict__ W1,
    const float* __restrict__ root2, const float* __restrict__ W2,
    unsigned short* __restrict__ wb,
    int g0, int g1, int g2, int g3) {
  int b = blockIdx.x, t = threadIdx.x;
  if (b < g0) {                       // zero cur, int4 per thread
    int i = b * 1024 + t * 4;
#pragma unroll
    for (int j = 0; j < 4; j++) if (i + j < RN) cur[i + j] = 0;
  } else if (b < g1) {                // graph bounds
    int i = (b - g0) * 256 + t;
    if (i >= N) return;
    int bb = batch[i];
    if (i == 0) { for (int g = 0; g <= bb; g++) gstart[g] = 0; }
    else { int pb = batch[i - 1]; for (int g = pb + 1; g <= bb; g++) gstart[g] = i; }
    if (i == N - 1) { for (int g = bb + 1; g <= G; g++) gstart[g] = N; }
  } else if (b < g2) {                // table fp32 -> bf16
    int i = (b - g1) * 256 + t;
    if (i < TN) tableb[i] = f2bf(table[i]);
  } else {                            // weights -> bf16 transposed [mat][n][k]
    int layer = (b < g3) ? 0 : 1;
    int idx = ((b - (layer ? g3 : g2)) * 256 + t);   // 0 .. 4*65536-1
    int mat = idx >> 16, rem = idx & 65535;
    int n = rem >> 8, k = rem & 255;
    const float* root = layer ? root2 : root1;
    const float* W = layer ? W2 : W1;
    const float* s = (mat == 0) ? root : (W + (size_t)(mat - 1) * 65536);
    wb[(size_t)layer * 4 * 65536 + idx] = f2bf(s[k * 256 + n]);
  }
}

// ---------------- per-(relation,node) in-edge counts ----------------
__global__ __launch_bounds__(256) void k_count_i(const int* __restrict__ dst,
    const int* __restrict__ et, int* __restrict__ cnt, int E, int N) {
  int e = blockIdx.x * 256 + threadIdx.x;
  if (e >= E) return;
  atomicAdd(&cnt[et[e] * N + dst[e]], 1);
}

// ---------------- 3-kernel scan chain (proven r11/r14) ----------------
__global__ __launch_bounds__(256) void k_scan1(const int* __restrict__ in,
    int* __restrict__ bsum, int n) {
  __shared__ int s[256];
  int base = blockIdx.x * SB, t = threadIdx.x;
  int a = 0;
#pragma unroll
  for (int j = 0; j < 4; j++) { int i = base + t * 4 + j; if (i < n) a += in[i]; }
  s[t] = a; __syncthreads();
  for (int o = 128; o > 0; o >>= 1) { if (t < o) s[t] += s[t + o]; __syncthreads(); }
  if (t == 0) bsum[blockIdx.x] = s[0];
}

__global__ __launch_bounds__(256) void k_scan2(int* __restrict__ bsum, int nb,
    int* __restrict__ total_out) {
  __shared__ int s[256];
  int t = threadIdx.x;
  int v[4]; int a = 0;
#pragma unroll
  for (int j = 0; j < 4; j++) {
    int i = t * 4 + j;
    v[j] = (i < nb) ? bsum[i] : 0;
    a += v[j];
  }
  s[t] = a; __syncthreads();
  for (int o = 1; o < 256; o <<= 1) {
    int x_ = (t >= o) ? s[t - o] : 0;
    __syncthreads();
    s[t] += x_;
    __syncthreads();
  }
  int excl = (t > 0) ? s[t - 1] : 0;
#pragma unroll
  for (int j = 0; j < 4; j++) {
    int i = t * 4 + j;
    if (i < nb) { bsum[i] = excl; excl += v[j]; }
  }
  if (t == 255) *total_out = s[255];
}

__global__ __launch_bounds__(256) void k_scan3(const int* __restrict__ in,
    const int* __restrict__ bsum, int* __restrict__ off, int* __restrict__ cur,
    int n) {
  __shared__ int s[256];
  int base = blockIdx.x * SB, t = threadIdx.x;
  int v[4]; int a = 0;
#pragma unroll
  for (int j = 0; j < 4; j++) {
    int i = base + t * 4 + j;
    v[j] = (i < n) ? in[i] : 0;
    a += v[j];
  }
  s[t] = a; __syncthreads();
  for (int o = 1; o < 256; o <<= 1) {
    int x_ = (t >= o) ? s[t - o] : 0;
    __syncthreads();
    s[t] += x_;
    __syncthreads();
  }
  int excl = (t > 0 ? s[t - 1] : 0) + bsum[blockIdx.x];
#pragma unroll
  for (int j = 0; j < 4; j++) {
    int i = base + t * 4 + j;
    if (i < n) { off[i] = excl; cur[i] = excl; excl += v[j]; }
  }
}

// CSR placement: esx[pos] = x[src] (L1 row id), ess[pos] = src (L2 row id)
__global__ __launch_bounds__(256) void k_place2(const int* __restrict__ src,
    const int* __restrict__ dst, const int* __restrict__ et,
    const int* __restrict__ x, int* __restrict__ cur,
    int* __restrict__ esx, int* __restrict__ ess, int E, int N) {
  int e = blockIdx.x * 256 + threadIdx.x;
  if (e >= E) return;
  int s = src[e];
  int pos = atomicAdd(&cur[et[e] * N + dst[e]], 1);
  esx[pos] = x[s];
  ess[pos] = s;
}

// ---------------- relation aggregation, 8 ids per wave (ILP batch) --------
__global__ __launch_bounds__(256) void k_agg(const unsigned short* __restrict__ h,
    const int* __restrict__ rows, const int* __restrict__ off,
    unsigned short* __restrict__ out, int RN) {
  const int wave = threadIdx.x >> 6, lane = threadIdx.x & 63;
  const int base = (blockIdx.x * 4 + wave) * 8;
  if (base >= RN) return;

  int lo[8], hi[8];
#pragma unroll
  for (int j = 0; j < 8; j++) {
    int id = base + j;
    lo[j] = (id < RN) ? off[id] : 0;
    hi[j] = (id < RN) ? off[id + 1] : 0;
  }

  int r0[8];
#pragma unroll
  for (int j = 0; j < 8; j++)
    r0[j] = (hi[j] > lo[j]) ? rows[lo[j]] : 0;

  ushort4 v0[8];
#pragma unroll
  for (int j = 0; j < 8; j++)
    v0[j] = (hi[j] > lo[j])
        ? *(const ushort4*)(h + (size_t)r0[j] * D + lane * 4)
        : make_ushort4(0, 0, 0, 0);

  float a[8][4];
#pragma unroll
  for (int j = 0; j < 8; j++) {
    a[j][0] = bf2f(v0[j].x); a[j][1] = bf2f(v0[j].y);
    a[j][2] = bf2f(v0[j].z); a[j][3] = bf2f(v0[j].w);
  }

#pragma unroll
  for (int j = 0; j < 8; j++) {
    for (int p = lo[j] + 1; p < hi[j]; ++p) {
      int r = rows[p];
      ushort4 v = *(const ushort4*)(h + (size_t)r * D + lane * 4);
      a[j][0] += bf2f(v.x); a[j][1] += bf2f(v.y);
      a[j][2] += bf2f(v.z); a[j][3] += bf2f(v.w);
    }
  }

#pragma unroll
  for (int j = 0; j < 8; j++) {
    int id = base + j;
    if (id >= RN) continue;
    int c = hi[j] - lo[j];
    float inv = 1.0f / (float)(c > 0 ? c : 1);
    ushort4 o;
    o.x = f2bf(a[j][0] * inv); o.y = f2bf(a[j][1] * inv);
    o.z = f2bf(a[j][2] * inv); o.w = f2bf(a[j][3] * inv);
    *(ushort4*)(out + (size_t)id * D + lane * 4) = o;
  }
}

// ---------------- fused K=1024 bf16 MFMA GEMM — LDS-FREE variant ----------
// Round-14 counters: LDS pipe 5x oversubscribed vs MFMA (11 b128 LDS ops vs
// 16 MFMA per wave-step across 8 waves/CU) -> MfmaUtil capped at 22%.
// Here A/B frags load global->VGPR directly in MFMA fragment layout
// (lane ml = row/col, chunk q*8: 16 x 64B fully-consumed segments/instr).
// B ([n][k] bf16) is L2-resident (2 MB, reused by all blocks). No LDS, no
// per-step barriers; one __syncthreads before the epilogue preserves the
// write-over-input-page safety (all waves' seg reads precede any C write).
// 256 thr = 4 waves, block tile 64 rows x 256 cols (full width), register
// double-buffered frags.
__global__ __launch_bounds__(256) void k_lgemm(
    const unsigned short* __restrict__ Aroot, const int* __restrict__ gidx,
    const unsigned short* agg, const unsigned short* __restrict__ wb,
    const float* __restrict__ bias, unsigned short* Cout, int M, int N) {
  const int tid = threadIdx.x;
  const int w = tid >> 6, lane = tid & 63;
  const int i0 = blockIdx.x * 64;
  const int ml = lane & 15, q = lane >> 4;
  const int qo = q * 8;

  // per-mi A row offsets (elements): gofs for seg0 (gidx), rofs for aggs
  int gofs[4], rofs[4];
#pragma unroll
  for (int mi = 0; mi < 4; mi++) {
    int r = i0 + mi * 16 + ml;
    int rc = (r < M) ? r : (M - 1);
    rofs[mi] = rc * 256;
    gofs[mi] = (gidx ? gidx[rc] : rc) * 256;
  }
  // per-ni B col offsets in wb [n][k]
  int bofs[4];
#pragma unroll
  for (int ni = 0; ni < 4; ni++)
    bofs[ni] = (w * 64 + ni * 16 + ml) * 256;

  floatx4 acc[4][4];
#pragma unroll
  for (int i = 0; i < 4; i++)
#pragma unroll
    for (int j = 0; j < 4; j++) acc[i][j] = (floatx4){0.f, 0.f, 0.f, 0.f};

  short8 aF[2][4], bF[2][4];
  // prefetch step 0 (seg 0, kt 0)
#pragma unroll
  for (int mi = 0; mi < 4; mi++)
    aF[0][mi] = *(const short8*)(Aroot + gofs[mi] + qo);
#pragma unroll
  for (int ni = 0; ni < 4; ni++)
    bF[0][ni] = *(const short8*)(wb + bofs[ni] + qo);

#pragma unroll
  for (int step = 0; step < 32; ++step) {
    const int cb = step & 1, nbuf = cb ^ 1;
    const int ns = (step < 31) ? step + 1 : 31;
    const int nseg = ns >> 3;                 // compile-time (full unroll)
    const int nkt = (ns & 7) * 32 + 0;
    const unsigned short* ab =
        (nseg == 0) ? Aroot : (agg + (size_t)(nseg - 1) * N * 256);
    const unsigned short* bb = wb + (size_t)nseg * 65536;
    // issue next step's 8 frag loads — fly under the MFMAs below
#pragma unroll
    for (int mi = 0; mi < 4; mi++) {
      int ofs = (nseg == 0) ? gofs[mi] : rofs[mi];
      aF[nbuf][mi] = *(const short8*)(ab + ofs + nkt + qo);
    }
#pragma unroll
    for (int ni = 0; ni < 4; ni++)
      bF[nbuf][ni] = *(const short8*)(bb + bofs[ni] + nkt + qo);

#pragma unroll
    for (int mi = 0; mi < 4; mi++)
#pragma unroll
      for (int ni = 0; ni < 4; ni++)
        acc[mi][ni] = __builtin_amdgcn_mfma_f32_16x16x32_bf16(
            aF[cb][mi], bF[cb][ni], acc[mi][ni], 0, 0, 0);
  }

  // all waves' A/agg reads done before any C write over an input page
  __syncthreads();

  // epilogue: bias + ReLU + bf16; C/D layout col=lane&15, row=q*4+reg
  float bv[4];
#pragma unroll
  for (int ni = 0; ni < 4; ni++) bv[ni] = bias[w * 64 + ni * 16 + ml];
#pragma unroll
  for (int mi = 0; mi < 4; mi++) {
#pragma unroll
    for (int ni = 0; ni < 4; ni++) {
      int col = w * 64 + ni * 16 + ml;
#pragma unroll
      for (int j = 0; j < 4; j++) {
        int row = i0 + mi * 16 + q * 4 + j;
        if (row < M) {
          float v = fmaxf(acc[mi][ni][j] + bv[ni], 0.f);
          Cout[(size_t)row * D + col] = f2bf(v);
        }
      }
    }
  }
}

// ---------------- fused graph mean-pool + linear head ----------------
__global__ __launch_bounds__(256) void k_poolfinal(
    const unsigned short* __restrict__ h, const int* __restrict__ gstart,
    const float* __restrict__ linW, const float* __restrict__ linb,
    float* __restrict__ out, int G) {
  __shared__ float red[4][D];
  __shared__ float sred[4][4];
  int g = blockIdx.x;
  int lo = gstart[g], hi = gstart[g + 1];
  int tid = threadIdx.x, wave = tid >> 6, lane = tid & 63;
  float a0 = 0.f, a1 = 0.f, a2 = 0.f, a3 = 0.f;
  for (int i = lo + wave; i < hi; i += 4) {
    ushort4 v = *(const ushort4*)(h + (size_t)i * D + lane * 4);
    a0 += bf2f(v.x); a1 += bf2f(v.y); a2 += bf2f(v.z); a3 += bf2f(v.w);
  }
  red[wave][lane * 4 + 0] = a0;
  red[wave][lane * 4 + 1] = a1;
  red[wave][lane * 4 + 2] = a2;
  red[wave][lane * 4 + 3] = a3;
  __syncthreads();
  float s = red[0][tid] + red[1][tid] + red[2][tid] + red[3][tid];
  float inv = (hi > lo) ? 1.0f / (float)(hi - lo) : 0.0f;
  float m = s * inv;                       // mean feature tid
  float4 wrow = *(const float4*)(linW + tid * 4);
  float p0 = m * wrow.x, p1 = m * wrow.y, p2 = m * wrow.z, p3 = m * wrow.w;
  for (int o = 32; o > 0; o >>= 1) {
    p0 += __shfl_down(p0, o, 64);
    p1 += __shfl_down(p1, o, 64);
    p2 += __shfl_down(p2, o, 64);
    p3 += __shfl_down(p3, o, 64);
  }
  if (lane == 0) {
    sred[wave][0] = p0; sred[wave][1] = p1;
    sred[wave][2] = p2; sred[wave][3] = p3;
  }
  __syncthreads();
  if (tid < 4)
    out[g * 4 + tid] = sred[0][tid] + sred[1][tid] + sred[2][tid] +
                       sred[3][tid] + linb[tid];
}

extern "C" void kernel_launch(void* const* d_in, const int* in_sizes, int n_in,
                              void* d_out, int out_size, void* d_ws, size_t ws_size,
                              hipStream_t stream) {
  const int*   x     = (const int*)d_in[0];
  const int*   ei    = (const int*)d_in[1];
  const int*   et    = (const int*)d_in[2];
  const int*   batch = (const int*)d_in[3];
  const float* table = (const float*)d_in[5];
  const float* W1    = (const float*)d_in[6];
  const float* root1 = (const float*)d_in[7];
  const float* b1    = (const float*)d_in[8];
  const float* W2    = (const float*)d_in[9];
  const float* root2 = (const float*)d_in[10];
  const float* b2    = (const float*)d_in[11];
  const float* linW  = (const float*)d_in[12];
  const float* linb  = (const float*)d_in[13];
  float* out = (float*)d_out;

  const int N = in_sizes[0];
  const int E = in_sizes[2];
  const int G = out_size / 4;
  const int VOC = in_sizes[5] / D;
  const int* src = ei;
  const int* dst = ei + E;
  const int RN = 3 * N;

  // ---- ws layout (~210 MB), page aliasing proven rounds 5-14 ----
  char* wsb = (char*)d_ws;
  size_t pg = (size_t)N * D * 2;
  unsigned short* P0 = (unsigned short*)wsb;
  unsigned short* P1 = (unsigned short*)(wsb + pg);
  unsigned short* P3 = (unsigned short*)(wsb + 3 * pg);
  unsigned short* wb = (unsigned short*)(wsb + 4 * pg);  // 2 layers x 4 mats
  int*   off    = (int*)(wb + 2 * 4 * 65536);
  int*   esx    = off + (RN + 1);       // L1 row ids (= x[src])
  int*   ess    = esx + E;              // L2 row ids (= src)
  int*   gstart = ess + E;
  unsigned short* tableb = P3;          // alias (dead before L2 agg writes P3)
  int* cur  = (int*)P0;                 // alias (dead before L1 agg writes P0)
  int* bsum = cur + RN;                 // alias

  const int nb = (RN + SB - 1) / SB;

  // ---- setup: one fused kernel for all independent prep ----
  int nbZero = (RN + 1023) / 1024;
  int nbBounds = (N + 255) / 256;
  int nbCvt = (VOC * D + 255) / 256;
  int g0 = nbZero, g1 = g0 + nbBounds, g2 = g1 + nbCvt, g3 = g2 + 1024;
  k_setup<<<g3 + 1024, 256, 0, stream>>>(cur, RN, batch, gstart, N, G,
      table, tableb, VOC * D, root1, W1, root2, W2, wb, g0, g1, g2, g3);

  k_count_i<<<(E + 255) / 256, 256, 0, stream>>>(dst, et, cur, E, N);
  k_scan1<<<nb, 256, 0, stream>>>(cur, bsum, RN);
  k_scan2<<<1, 256, 0, stream>>>(bsum, nb, off + RN);
  k_scan3<<<nb, 256, 0, stream>>>(cur, bsum, off, cur, RN);
  k_place2<<<(E + 255) / 256, 256, 0, stream>>>(src, dst, et, x, cur, esx, ess, E, N);

  const int gagg = (RN + 31) / 32;      // 8 ids/wave x 4 waves
  const int ggemm = (N + 63) / 64;      // 64-row blocks, full 256-col width

  // ---- layer 1 ----
  k_agg<<<gagg, 256, 0, stream>>>(tableb, esx, off, P0, RN);
  k_lgemm<<<ggemm, 256, 0, stream>>>(tableb, x, P0, wb, b1, P0, N, N);
  // ---- layer 2 ----
  k_agg<<<gagg, 256, 0, stream>>>(P0, ess, off, P1, RN);
  k_lgemm<<<ggemm, 256, 0, stream>>>(P0, nullptr, P1, wb + 4 * 65536, b2, P1, N, N);

  // ---- pool + head fused ----
  k_poolfinal<<<G, 256, 0, stream>>>(P1, gstart, linW, linb, out, G);
}

// Round 16
// 432.903 us; speedup vs baseline: 1.6176x; 1.6176x over previous
//
#include <hip/hip_runtime.h>

#define D 256
#define SB 1024
typedef __attribute__((ext_vector_type(8))) short short8;
typedef __attribute__((ext_vector_type(4))) float floatx4;

__device__ __forceinline__ unsigned short f2bf(float f) {
  unsigned int u = __float_as_uint(f);
  u = (u + 0x7FFF + ((u >> 16) & 1)) >> 16;   // RNE
  return (unsigned short)u;
}
__device__ __forceinline__ float bf2f(unsigned short h) {
  return __uint_as_float(((unsigned int)h) << 16);
}

// ---------------- fused independent setup: zero | bounds | cvt | cvt_w x2 --
__global__ __launch_bounds__(256) void k_setup(
    int* __restrict__ cur, int RN,
    const int* __restrict__ batch, int* __restrict__ gstart, int N, int G,
    const float* __restrict__ table, unsigned short* __restrict__ tableb, int TN,
    const float* __restrict__ root1, const float* __restrict__ W1,
    const float* __restrict__ root2, const float* __restrict__ W2,
    unsigned short* __restrict__ wb,
    int g0, int g1, int g2, int g3) {
  int b = blockIdx.x, t = threadIdx.x;
  if (b < g0) {                       // zero cur, int4 per thread
    int i = b * 1024 + t * 4;
#pragma unroll
    for (int j = 0; j < 4; j++) if (i + j < RN) cur[i + j] = 0;
  } else if (b < g1) {                // graph bounds
    int i = (b - g0) * 256 + t;
    if (i >= N) return;
    int bb = batch[i];
    if (i == 0) { for (int g = 0; g <= bb; g++) gstart[g] = 0; }
    else { int pb = batch[i - 1]; for (int g = pb + 1; g <= bb; g++) gstart[g] = i; }
    if (i == N - 1) { for (int g = bb + 1; g <= G; g++) gstart[g] = N; }
  } else if (b < g2) {                // table fp32 -> bf16
    int i = (b - g1) * 256 + t;
    if (i < TN) tableb[i] = f2bf(table[i]);
  } else {                            // weights -> bf16 transposed [mat][n][k]
    int layer = (b < g3) ? 0 : 1;
    int idx = ((b - (layer ? g3 : g2)) * 256 + t);   // 0 .. 4*65536-1
    int mat = idx >> 16, rem = idx & 65535;
    int n = rem >> 8, k = rem & 255;
    const float* root = layer ? root2 : root1;
    const float* W = layer ? W2 : W1;
    const float* s = (mat == 0) ? root : (W + (size_t)(mat - 1) * 65536);
    wb[(size_t)layer * 4 * 65536 + idx] = f2bf(s[k * 256 + n]);
  }
}

// ---------------- per-(relation,node) in-edge counts ----------------
__global__ __launch_bounds__(256) void k_count_i(const int* __restrict__ dst,
    const int* __restrict__ et, int* __restrict__ cnt, int E, int N) {
  int e = blockIdx.x * 256 + threadIdx.x;
  if (e >= E) return;
  atomicAdd(&cnt[et[e] * N + dst[e]], 1);
}

// ---------------- 3-kernel scan chain (proven r11/r14; lookback variant
// regressed ~21 us and volatile flag spins are unsafe across non-coherent
// XCD L2s; cooperative grid.sync costs ~100 us/barrier — do not revisit) ----
__global__ __launch_bounds__(256) void k_scan1(const int* __restrict__ in,
    int* __restrict__ bsum, int n) {
  __shared__ int s[256];
  int base = blockIdx.x * SB, t = threadIdx.x;
  int a = 0;
#pragma unroll
  for (int j = 0; j < 4; j++) { int i = base + t * 4 + j; if (i < n) a += in[i]; }
  s[t] = a; __syncthreads();
  for (int o = 128; o > 0; o >>= 1) { if (t < o) s[t] += s[t + o]; __syncthreads(); }
  if (t == 0) bsum[blockIdx.x] = s[0];
}

__global__ __launch_bounds__(256) void k_scan2(int* __restrict__ bsum, int nb,
    int* __restrict__ total_out) {
  __shared__ int s[256];
  int t = threadIdx.x;
  int v[4]; int a = 0;
#pragma unroll
  for (int j = 0; j < 4; j++) {
    int i = t * 4 + j;
    v[j] = (i < nb) ? bsum[i] : 0;
    a += v[j];
  }
  s[t] = a; __syncthreads();
  for (int o = 1; o < 256; o <<= 1) {
    int x_ = (t >= o) ? s[t - o] : 0;
    __syncthreads();
    s[t] += x_;
    __syncthreads();
  }
  int excl = (t > 0) ? s[t - 1] : 0;
#pragma unroll
  for (int j = 0; j < 4; j++) {
    int i = t * 4 + j;
    if (i < nb) { bsum[i] = excl; excl += v[j]; }
  }
  if (t == 255) *total_out = s[255];
}

__global__ __launch_bounds__(256) void k_scan3(const int* __restrict__ in,
    const int* __restrict__ bsum, int* __restrict__ off, int* __restrict__ cur,
    int n) {
  __shared__ int s[256];
  int base = blockIdx.x * SB, t = threadIdx.x;
  int v[4]; int a = 0;
#pragma unroll
  for (int j = 0; j < 4; j++) {
    int i = base + t * 4 + j;
    v[j] = (i < n) ? in[i] : 0;
    a += v[j];
  }
  s[t] = a; __syncthreads();
  for (int o = 1; o < 256; o <<= 1) {
    int x_ = (t >= o) ? s[t - o] : 0;
    __syncthreads();
    s[t] += x_;
    __syncthreads();
  }
  int excl = (t > 0 ? s[t - 1] : 0) + bsum[blockIdx.x];
#pragma unroll
  for (int j = 0; j < 4; j++) {
    int i = base + t * 4 + j;
    if (i < n) { off[i] = excl; cur[i] = excl; excl += v[j]; }
  }
}

// CSR placement: esx[pos] = x[src] (L1 row id), ess[pos] = src (L2 row id)
__global__ __launch_bounds__(256) void k_place2(const int* __restrict__ src,
    const int* __restrict__ dst, const int* __restrict__ et,
    const int* __restrict__ x, int* __restrict__ cur,
    int* __restrict__ esx, int* __restrict__ ess, int E, int N) {
  int e = blockIdx.x * 256 + threadIdx.x;
  if (e >= E) return;
  int s = src[e];
  int pos = atomicAdd(&cur[et[e] * N + dst[e]], 1);
  esx[pos] = x[s];
  ess[pos] = s;
}

// ---------------- relation aggregation, 8 ids per wave (ILP batch) --------
__global__ __launch_bounds__(256) void k_agg(const unsigned short* __restrict__ h,
    const int* __restrict__ rows, const int* __restrict__ off,
    unsigned short* __restrict__ out, int RN) {
  const int wave = threadIdx.x >> 6, lane = threadIdx.x & 63;
  const int base = (blockIdx.x * 4 + wave) * 8;
  if (base >= RN) return;

  int lo[8], hi[8];
#pragma unroll
  for (int j = 0; j < 8; j++) {
    int id = base + j;
    lo[j] = (id < RN) ? off[id] : 0;
    hi[j] = (id < RN) ? off[id + 1] : 0;
  }

  int r0[8];
#pragma unroll
  for (int j = 0; j < 8; j++)
    r0[j] = (hi[j] > lo[j]) ? rows[lo[j]] : 0;

  ushort4 v0[8];
#pragma unroll
  for (int j = 0; j < 8; j++)
    v0[j] = (hi[j] > lo[j])
        ? *(const ushort4*)(h + (size_t)r0[j] * D + lane * 4)
        : make_ushort4(0, 0, 0, 0);

  float a[8][4];
#pragma unroll
  for (int j = 0; j < 8; j++) {
    a[j][0] = bf2f(v0[j].x); a[j][1] = bf2f(v0[j].y);
    a[j][2] = bf2f(v0[j].z); a[j][3] = bf2f(v0[j].w);
  }

#pragma unroll
  for (int j = 0; j < 8; j++) {
    for (int p = lo[j] + 1; p < hi[j]; ++p) {
      int r = rows[p];
      ushort4 v = *(const ushort4*)(h + (size_t)r * D + lane * 4);
      a[j][0] += bf2f(v.x); a[j][1] += bf2f(v.y);
      a[j][2] += bf2f(v.z); a[j][3] += bf2f(v.w);
    }
  }

#pragma unroll
  for (int j = 0; j < 8; j++) {
    int id = base + j;
    if (id >= RN) continue;
    int c = hi[j] - lo[j];
    float inv = 1.0f / (float)(c > 0 ? c : 1);
    ushort4 o;
    o.x = f2bf(a[j][0] * inv); o.y = f2bf(a[j][1] * inv);
    o.z = f2bf(a[j][2] * inv); o.w = f2bf(a[j][3] * inv);
    *(ushort4*)(out + (size_t)id * D + lane * 4) = o;
  }
}

// ---------------- fused K=1024 bf16 MFMA GEMM, 128x256 block, 8 waves ------
// PROVEN OPTIMUM (96.6 us, rounds 8/11/14): BK=32, 30 KB LDS, VGPR 56.
// The LDS round-trip is a bandwidth multiplier, not overhead:
//  - r15 LDS-free (direct global->VGPR frags): 4 MB/block redundant L2
//    traffic -> 233 us, L2-bound.
//  - r9 BK=64: reg spill -> 245 us. r7 wider wave tiles: occupancy -> 166 us.
//  - r12 cooperative grid.sync: ~100 us/barrier.
// SQ_LDS_BANK_CONFLICT ~1.1e7 is intrinsic b128 multi-phase service.
__global__ __launch_bounds__(512) void k_lgemm(
    const unsigned short* __restrict__ Aroot, const int* __restrict__ gidx,
    const unsigned short* agg, const unsigned short* __restrict__ wb,
    const float* __restrict__ bias, unsigned short* Cout, int M, int N) {
  __shared__ unsigned short AsU[128 * 40];       // 10 KB [row][k] pad->40
  __shared__ unsigned short BsU[256 * 40];       // 20 KB [n][k]   pad->40
  const int tid = threadIdx.x;
  const int w = tid >> 6, lane = tid & 63;
  const int wr = w >> 2, wc = w & 3;             // wave grid 2x4
  const int i0 = blockIdx.x * 128;
  const int ml = lane & 15, q = lane >> 4;

  const int srow = tid >> 2;       // 0..127
  const int schunk = tid & 3;      // 16B chunk within 64B k-slice
  int r0 = i0 + srow;
  int r0c = (r0 < M) ? r0 : (M - 1);
  const int rowA0 = gidx ? gidx[r0c] : r0c;

  const unsigned short* a0base[4];
  a0base[0] = Aroot + (size_t)rowA0 * D + schunk * 8;
#pragma unroll
  for (int r = 0; r < 3; r++)
    a0base[r + 1] = agg + ((size_t)r * N + r0c) * D + schunk * 8;

  floatx4 acc[4][4];
#pragma unroll
  for (int i = 0; i < 4; i++)
#pragma unroll
    for (int j = 0; j < 4; j++) acc[i][j] = (floatx4){0.f, 0.f, 0.f, 0.f};

  // prefetch registers (step 0)
  uint4 av0, bv0, bv1;
  {
    av0 = *(const uint4*)(a0base[0]);
    const unsigned short* bb = wb + (size_t)srow * D + schunk * 8;
    bv0 = *(const uint4*)(bb);
    bv1 = *(const uint4*)(bb + 128 * D);
  }

  for (int step = 0; step < 32; ++step) {
    __syncthreads();   // previous step's LDS consumers done
    *(uint4*)&AsU[srow * 40 + schunk * 8] = av0;
    *(uint4*)&BsU[srow * 40 + schunk * 8] = bv0;
    *(uint4*)&BsU[(srow + 128) * 40 + schunk * 8] = bv1;
    __syncthreads();

    // issue next step's loads now — they fly under the compute below
    {
      int ns = (step < 31) ? step + 1 : 31;
      int seg = ns >> 3, kloc = (ns & 7) * 32;
      av0 = *(const uint4*)(a0base[seg] + kloc);
      const unsigned short* bb =
          wb + (size_t)seg * 65536 + (size_t)srow * D + schunk * 8 + kloc;
      bv0 = *(const uint4*)(bb);
      bv1 = *(const uint4*)(bb + 128 * D);
    }

    short8 aF[4], bF[4];
#pragma unroll
    for (int mi = 0; mi < 4; mi++)
      aF[mi] = *(const short8*)&AsU[(wr * 64 + mi * 16 + ml) * 40 + q * 8];
#pragma unroll
    for (int ni = 0; ni < 4; ni++)
      bF[ni] = *(const short8*)&BsU[(wc * 64 + ni * 16 + ml) * 40 + q * 8];
#pragma unroll
    for (int mi = 0; mi < 4; mi++)
#pragma unroll
      for (int ni = 0; ni < 4; ni++)
        acc[mi][ni] = __builtin_amdgcn_mfma_f32_16x16x32_bf16(
            aF[mi], bF[ni], acc[mi][ni], 0, 0, 0);
  }

  // epilogue: bias + ReLU + bf16; C/D layout col=lane&15, row=q*4+reg
  float bv[4];
#pragma unroll
  for (int ni = 0; ni < 4; ni++) bv[ni] = bias[wc * 64 + ni * 16 + ml];
#pragma unroll
  for (int mi = 0; mi < 4; mi++) {
#pragma unroll
    for (int ni = 0; ni < 4; ni++) {
      int col = wc * 64 + ni * 16 + ml;
#pragma unroll
      for (int j = 0; j < 4; j++) {
        int row = i0 + wr * 64 + mi * 16 + q * 4 + j;
        if (row < M) {
          float v = fmaxf(acc[mi][ni][j] + bv[ni], 0.f);
          Cout[(size_t)row * D + col] = f2bf(v);
        }
      }
    }
  }
}

// ---------------- fused graph mean-pool + linear head ----------------
__global__ __launch_bounds__(256) void k_poolfinal(
    const unsigned short* __restrict__ h, const int* __restrict__ gstart,
    const float* __restrict__ linW, const float* __restrict__ linb,
    float* __restrict__ out, int G) {
  __shared__ float red[4][D];
  __shared__ float sred[4][4];
  int g = blockIdx.x;
  int lo = gstart[g], hi = gstart[g + 1];
  int tid = threadIdx.x, wave = tid >> 6, lane = tid & 63;
  float a0 = 0.f, a1 = 0.f, a2 = 0.f, a3 = 0.f;
  for (int i = lo + wave; i < hi; i += 4) {
    ushort4 v = *(const ushort4*)(h + (size_t)i * D + lane * 4);
    a0 += bf2f(v.x); a1 += bf2f(v.y); a2 += bf2f(v.z); a3 += bf2f(v.w);
  }
  red[wave][lane * 4 + 0] = a0;
  red[wave][lane * 4 + 1] = a1;
  red[wave][lane * 4 + 2] = a2;
  red[wave][lane * 4 + 3] = a3;
  __syncthreads();
  float s = red[0][tid] + red[1][tid] + red[2][tid] + red[3][tid];
  float inv = (hi > lo) ? 1.0f / (float)(hi - lo) : 0.0f;
  float m = s * inv;                       // mean feature tid
  float4 wrow = *(const float4*)(linW + tid * 4);
  float p0 = m * wrow.x, p1 = m * wrow.y, p2 = m * wrow.z, p3 = m * wrow.w;
  for (int o = 32; o > 0; o >>= 1) {
    p0 += __shfl_down(p0, o, 64);
    p1 += __shfl_down(p1, o, 64);
    p2 += __shfl_down(p2, o, 64);
    p3 += __shfl_down(p3, o, 64);
  }
  if (lane == 0) {
    sred[wave][0] = p0; sred[wave][1] = p1;
    sred[wave][2] = p2; sred[wave][3] = p3;
  }
  __syncthreads();
  if (tid < 4)
    out[g * 4 + tid] = sred[0][tid] + sred[1][tid] + sred[2][tid] +
                       sred[3][tid] + linb[tid];
}

extern "C" void kernel_launch(void* const* d_in, const int* in_sizes, int n_in,
                              void* d_out, int out_size, void* d_ws, size_t ws_size,
                              hipStream_t stream) {
  const int*   x     = (const int*)d_in[0];
  const int*   ei    = (const int*)d_in[1];
  const int*   et    = (const int*)d_in[2];
  const int*   batch = (const int*)d_in[3];
  const float* table = (const float*)d_in[5];
  const float* W1    = (const float*)d_in[6];
  const float* root1 = (const float*)d_in[7];
  const float* b1    = (const float*)d_in[8];
  const float* W2    = (const float*)d_in[9];
  const float* root2 = (const float*)d_in[10];
  const float* b2    = (const float*)d_in[11];
  const float* linW  = (const float*)d_in[12];
  const float* linb  = (const float*)d_in[13];
  float* out = (float*)d_out;

  const int N = in_sizes[0];
  const int E = in_sizes[2];
  const int G = out_size / 4;
  const int VOC = in_sizes[5] / D;
  const int* src = ei;
  const int* dst = ei + E;
  const int RN = 3 * N;

  // ---- ws layout (~210 MB), page aliasing proven rounds 5-15 ----
  char* wsb = (char*)d_ws;
  size_t pg = (size_t)N * D * 2;
  unsigned short* P0 = (unsigned short*)wsb;
  unsigned short* P1 = (unsigned short*)(wsb + pg);
  unsigned short* P3 = (unsigned short*)(wsb + 3 * pg);
  unsigned short* wb = (unsigned short*)(wsb + 4 * pg);  // 2 layers x 4 mats
  int*   off    = (int*)(wb + 2 * 4 * 65536);
  int*   esx    = off + (RN + 1);       // L1 row ids (= x[src])
  int*   ess    = esx + E;              // L2 row ids (= src)
  int*   gstart = ess + E;
  unsigned short* tableb = P3;          // alias (dead before L2 agg writes P3)
  int* cur  = (int*)P0;                 // alias (dead before L1 agg writes P0)
  int* bsum = cur + RN;                 // alias

  const int nb = (RN + SB - 1) / SB;

  // ---- setup: one fused kernel for all independent prep ----
  int nbZero = (RN + 1023) / 1024;
  int nbBounds = (N + 255) / 256;
  int nbCvt = (VOC * D + 255) / 256;
  int g0 = nbZero, g1 = g0 + nbBounds, g2 = g1 + nbCvt, g3 = g2 + 1024;
  k_setup<<<g3 + 1024, 256, 0, stream>>>(cur, RN, batch, gstart, N, G,
      table, tableb, VOC * D, root1, W1, root2, W2, wb, g0, g1, g2, g3);

  k_count_i<<<(E + 255) / 256, 256, 0, stream>>>(dst, et, cur, E, N);
  k_scan1<<<nb, 256, 0, stream>>>(cur, bsum, RN);
  k_scan2<<<1, 256, 0, stream>>>(bsum, nb, off + RN);
  k_scan3<<<nb, 256, 0, stream>>>(cur, bsum, off, cur, RN);
  k_place2<<<(E + 255) / 256, 256, 0, stream>>>(src, dst, et, x, cur, esx, ess, E, N);

  const int gagg = (RN + 31) / 32;      // 8 ids/wave x 4 waves
  const int ggemm = (N + 127) / 128;

  // ---- layer 1 ----
  k_agg<<<gagg, 256, 0, stream>>>(tableb, esx, off, P0, RN);
  k_lgemm<<<ggemm, 512, 0, stream>>>(tableb, x, P0, wb, b1, P0, N, N);
  // ---- layer 2 ----
  k_agg<<<gagg, 256, 0, stream>>>(P0, ess, off, P1, RN);
  k_lgemm<<<ggemm, 512, 0, stream>>>(P0, nullptr, P1, wb + 4 * 65536, b2, P1, N, N);

  // ---- pool + head fused ----
  k_poolfinal<<<G, 256, 0, stream>>>(P1, gstart, linW, linb, out, G);
}

// Round 17
// 405.480 us; speedup vs baseline: 1.7270x; 1.0676x over previous
//
#include <hip/hip_runtime.h>

#define D 256
#define SB 1024
typedef __attribute__((ext_vector_type(8))) short short8;
typedef __attribute__((ext_vector_type(4))) float floatx4;

__device__ __forceinline__ unsigned short f2bf(float f) {
  unsigned int u = __float_as_uint(f);
  u = (u + 0x7FFF + ((u >> 16) & 1)) >> 16;   // RNE
  return (unsigned short)u;
}
__device__ __forceinline__ float bf2f(unsigned short h) {
  return __uint_as_float(((unsigned int)h) << 16);
}

// async global->LDS, 16B per lane; LDS dest = wave-uniform base + lane*16
__device__ __forceinline__ void glds16(const void* g, void* l) {
  __builtin_amdgcn_global_load_lds(
      (const __attribute__((address_space(1))) unsigned int*)g,
      (__attribute__((address_space(3))) unsigned int*)l, 16, 0, 0);
}

// ---------------- fused independent setup: zero | bounds | cvt | cvt_w x2 --
__global__ __launch_bounds__(256) void k_setup(
    int* __restrict__ cur, int RN,
    const int* __restrict__ batch, int* __restrict__ gstart, int N, int G,
    const float* __restrict__ table, unsigned short* __restrict__ tableb, int TN,
    const float* __restrict__ root1, const float* __restrict__ W1,
    const float* __restrict__ root2, const float* __restrict__ W2,
    unsigned short* __restrict__ wb,
    int g0, int g1, int g2, int g3) {
  int b = blockIdx.x, t = threadIdx.x;
  if (b < g0) {                       // zero cur, int4 per thread
    int i = b * 1024 + t * 4;
#pragma unroll
    for (int j = 0; j < 4; j++) if (i + j < RN) cur[i + j] = 0;
  } else if (b < g1) {                // graph bounds
    int i = (b - g0) * 256 + t;
    if (i >= N) return;
    int bb = batch[i];
    if (i == 0) { for (int g = 0; g <= bb; g++) gstart[g] = 0; }
    else { int pb = batch[i - 1]; for (int g = pb + 1; g <= bb; g++) gstart[g] = i; }
    if (i == N - 1) { for (int g = bb + 1; g <= G; g++) gstart[g] = N; }
  } else if (b < g2) {                // table fp32 -> bf16
    int i = (b - g1) * 256 + t;
    if (i < TN) tableb[i] = f2bf(table[i]);
  } else {                            // weights -> bf16 transposed [mat][n][k]
    int layer = (b < g3) ? 0 : 1;
    int idx = ((b - (layer ? g3 : g2)) * 256 + t);   // 0 .. 4*65536-1
    int mat = idx >> 16, rem = idx & 65535;
    int n = rem >> 8, k = rem & 255;
    const float* root = layer ? root2 : root1;
    const float* W = layer ? W2 : W1;
    const float* s = (mat == 0) ? root : (W + (size_t)(mat - 1) * 65536);
    wb[(size_t)layer * 4 * 65536 + idx] = f2bf(s[k * 256 + n]);
  }
}

// ---------------- per-(relation,node) in-edge counts ----------------
__global__ __launch_bounds__(256) void k_count_i(const int* __restrict__ dst,
    const int* __restrict__ et, int* __restrict__ cnt, int E, int N) {
  int e = blockIdx.x * 256 + threadIdx.x;
  if (e >= E) return;
  atomicAdd(&cnt[et[e] * N + dst[e]], 1);
}

// ---------------- 3-kernel scan chain (proven r11/r14) ----------------
__global__ __launch_bounds__(256) void k_scan1(const int* __restrict__ in,
    int* __restrict__ bsum, int n) {
  __shared__ int s[256];
  int base = blockIdx.x * SB, t = threadIdx.x;
  int a = 0;
#pragma unroll
  for (int j = 0; j < 4; j++) { int i = base + t * 4 + j; if (i < n) a += in[i]; }
  s[t] = a; __syncthreads();
  for (int o = 128; o > 0; o >>= 1) { if (t < o) s[t] += s[t + o]; __syncthreads(); }
  if (t == 0) bsum[blockIdx.x] = s[0];
}

__global__ __launch_bounds__(256) void k_scan2(int* __restrict__ bsum, int nb,
    int* __restrict__ total_out) {
  __shared__ int s[256];
  int t = threadIdx.x;
  int v[4]; int a = 0;
#pragma unroll
  for (int j = 0; j < 4; j++) {
    int i = t * 4 + j;
    v[j] = (i < nb) ? bsum[i] : 0;
    a += v[j];
  }
  s[t] = a; __syncthreads();
  for (int o = 1; o < 256; o <<= 1) {
    int x_ = (t >= o) ? s[t - o] : 0;
    __syncthreads();
    s[t] += x_;
    __syncthreads();
  }
  int excl = (t > 0) ? s[t - 1] : 0;
#pragma unroll
  for (int j = 0; j < 4; j++) {
    int i = t * 4 + j;
    if (i < nb) { bsum[i] = excl; excl += v[j]; }
  }
  if (t == 255) *total_out = s[255];
}

__global__ __launch_bounds__(256) void k_scan3(const int* __restrict__ in,
    const int* __restrict__ bsum, int* __restrict__ off, int* __restrict__ cur,
    int n) {
  __shared__ int s[256];
  int base = blockIdx.x * SB, t = threadIdx.x;
  int v[4]; int a = 0;
#pragma unroll
  for (int j = 0; j < 4; j++) {
    int i = base + t * 4 + j;
    v[j] = (i < n) ? in[i] : 0;
    a += v[j];
  }
  s[t] = a; __syncthreads();
  for (int o = 1; o < 256; o <<= 1) {
    int x_ = (t >= o) ? s[t - o] : 0;
    __syncthreads();
    s[t] += x_;
    __syncthreads();
  }
  int excl = (t > 0 ? s[t - 1] : 0) + bsum[blockIdx.x];
#pragma unroll
  for (int j = 0; j < 4; j++) {
    int i = base + t * 4 + j;
    if (i < n) { off[i] = excl; cur[i] = excl; excl += v[j]; }
  }
}

// CSR placement: esx[pos] = x[src] (L1 row id), ess[pos] = src (L2 row id)
__global__ __launch_bounds__(256) void k_place2(const int* __restrict__ src,
    const int* __restrict__ dst, const int* __restrict__ et,
    const int* __restrict__ x, int* __restrict__ cur,
    int* __restrict__ esx, int* __restrict__ ess, int E, int N) {
  int e = blockIdx.x * 256 + threadIdx.x;
  if (e >= E) return;
  int s = src[e];
  int pos = atomicAdd(&cur[et[e] * N + dst[e]], 1);
  esx[pos] = x[s];
  ess[pos] = s;
}

// ---------------- relation aggregation, 8 ids per wave (ILP batch) --------
__global__ __launch_bounds__(256) void k_agg(const unsigned short* __restrict__ h,
    const int* __restrict__ rows, const int* __restrict__ off,
    unsigned short* __restrict__ out, int RN) {
  const int wave = threadIdx.x >> 6, lane = threadIdx.x & 63;
  const int base = (blockIdx.x * 4 + wave) * 8;
  if (base >= RN) return;

  int lo[8], hi[8];
#pragma unroll
  for (int j = 0; j < 8; j++) {
    int id = base + j;
    lo[j] = (id < RN) ? off[id] : 0;
    hi[j] = (id < RN) ? off[id + 1] : 0;
  }

  int r0[8];
#pragma unroll
  for (int j = 0; j < 8; j++)
    r0[j] = (hi[j] > lo[j]) ? rows[lo[j]] : 0;

  ushort4 v0[8];
#pragma unroll
  for (int j = 0; j < 8; j++)
    v0[j] = (hi[j] > lo[j])
        ? *(const ushort4*)(h + (size_t)r0[j] * D + lane * 4)
        : make_ushort4(0, 0, 0, 0);

  float a[8][4];
#pragma unroll
  for (int j = 0; j < 8; j++) {
    a[j][0] = bf2f(v0[j].x); a[j][1] = bf2f(v0[j].y);
    a[j][2] = bf2f(v0[j].z); a[j][3] = bf2f(v0[j].w);
  }

#pragma unroll
  for (int j = 0; j < 8; j++) {
    for (int p = lo[j] + 1; p < hi[j]; ++p) {
      int r = rows[p];
      ushort4 v = *(const ushort4*)(h + (size_t)r * D + lane * 4);
      a[j][0] += bf2f(v.x); a[j][1] += bf2f(v.y);
      a[j][2] += bf2f(v.z); a[j][3] += bf2f(v.w);
    }
  }

#pragma unroll
  for (int j = 0; j < 8; j++) {
    int id = base + j;
    if (id >= RN) continue;
    int c = hi[j] - lo[j];
    float inv = 1.0f / (float)(c > 0 ? c : 1);
    ushort4 o;
    o.x = f2bf(a[j][0] * inv); o.y = f2bf(a[j][1] * inv);
    o.z = f2bf(a[j][2] * inv); o.w = f2bf(a[j][3] * inv);
    *(ushort4*)(out + (size_t)id * D + lane * 4) = o;
  }
}

// ---------------- fused K=1024 bf16 MFMA GEMM, glds staging ---------------
// m97-style: staging via global_load_lds width=16 (no VGPR round-trip, no
// wave-issued ds_writes on the LDS pipe). LDS layouts UNPADDED contiguous
// (glds requires dest = wave-uniform base + lane*16). Frag reads at stride
// 32 ushorts alias only 2-way (free, m136). 128x256 block, 8 waves (2x4).
// History: r9 BK=64 spill 245us; r15 LDS-free L2-bound 233us; r12 grid.sync
// 100us/barrier; padded+reg-prefetch baseline (r8/r11/r14/r16) = 96.6us.
__global__ __launch_bounds__(512) void k_lgemm(
    const unsigned short* __restrict__ Aroot, const int* __restrict__ gidx,
    const unsigned short* agg, const unsigned short* __restrict__ wb,
    const float* __restrict__ bias, unsigned short* Cout, int M, int N) {
  __shared__ unsigned short AsU[128 * 32];       // 8 KB  [row][k] contiguous
  __shared__ unsigned short BsU[256 * 32];       // 16 KB [n][k]   contiguous
  const int tid = threadIdx.x;
  const int w = tid >> 6, lane = tid & 63;
  const int wr = w >> 2, wc = w & 3;             // wave grid 2x4
  const int i0 = blockIdx.x * 128;
  const int ml = lane & 15, q = lane >> 4;

  // A staging: wave w stages rows w*16..w*16+15 (1 KB / instr).
  // lane l -> row w*16 + l/4, 16B chunk l%4. LDS dest uniform: AsU + w*512.
  const int arow = w * 16 + (lane >> 2);
  const int achunk = lane & 3;
  int ra = i0 + arow;
  int rac = (ra < M) ? ra : (M - 1);
  const int rowA0 = gidx ? gidx[rac] : rac;
  const unsigned short* a0base[4];
  a0base[0] = Aroot + (size_t)rowA0 * D + achunk * 8;
#pragma unroll
  for (int r = 0; r < 3; r++)
    a0base[r + 1] = agg + ((size_t)r * N + rac) * D + achunk * 8;

  // B staging: wave w stages rows w*32..w*32+31 (2 instrs of 1 KB).
  const int brow = w * 32 + (lane >> 2);
  const int bchunk = lane & 3;
  const size_t bofs = (size_t)brow * D + bchunk * 8;

  floatx4 acc[4][4];
#pragma unroll
  for (int i = 0; i < 4; i++)
#pragma unroll
    for (int j = 0; j < 4; j++) acc[i][j] = (floatx4){0.f, 0.f, 0.f, 0.f};

  unsigned short* aldst = &AsU[w * 512];          // wave-uniform
  unsigned short* bldst0 = &BsU[w * 1024];
  unsigned short* bldst1 = &BsU[w * 1024 + 512];

  for (int step = 0; step < 32; ++step) {
    const int seg = step >> 3, kloc = (step & 7) * 32;
    __syncthreads();                    // previous step's LDS reads done
    glds16(a0base[seg] + kloc, aldst);
    const unsigned short* bb = wb + (size_t)seg * 65536 + bofs + kloc;
    glds16(bb, bldst0);
    glds16(bb + 16 * D, bldst1);
    __syncthreads();                    // vmcnt drained -> LDS populated

    short8 aF[4], bF[4];
#pragma unroll
    for (int mi = 0; mi < 4; mi++)
      aF[mi] = *(const short8*)&AsU[(wr * 64 + mi * 16 + ml) * 32 + q * 8];
#pragma unroll
    for (int ni = 0; ni < 4; ni++)
      bF[ni] = *(const short8*)&BsU[(wc * 64 + ni * 16 + ml) * 32 + q * 8];
#pragma unroll
    for (int mi = 0; mi < 4; mi++)
#pragma unroll
      for (int ni = 0; ni < 4; ni++)
        acc[mi][ni] = __builtin_amdgcn_mfma_f32_16x16x32_bf16(
            aF[mi], bF[ni], acc[mi][ni], 0, 0, 0);
  }

  // per-block read-before-write over input pages holds: block b reads/writes
  // only rows [i0, i0+128) of the aliased page, and its reads all precede
  // its epilogue writes.
  __syncthreads();

  // epilogue: bias + ReLU + bf16; C/D layout col=lane&15, row=q*4+reg
  float bv[4];
#pragma unroll
  for (int ni = 0; ni < 4; ni++) bv[ni] = bias[wc * 64 + ni * 16 + ml];
#pragma unroll
  for (int mi = 0; mi < 4; mi++) {
#pragma unroll
    for (int ni = 0; ni < 4; ni++) {
      int col = wc * 64 + ni * 16 + ml;
#pragma unroll
      for (int j = 0; j < 4; j++) {
        int row = i0 + wr * 64 + mi * 16 + q * 4 + j;
        if (row < M) {
          float v = fmaxf(acc[mi][ni][j] + bv[ni], 0.f);
          Cout[(size_t)row * D + col] = f2bf(v);
        }
      }
    }
  }
}

// ---------------- fused graph mean-pool + linear head ----------------
__global__ __launch_bounds__(256) void k_poolfinal(
    const unsigned short* __restrict__ h, const int* __restrict__ gstart,
    const float* __restrict__ linW, const float* __restrict__ linb,
    float* __restrict__ out, int G) {
  __shared__ float red[4][D];
  __shared__ float sred[4][4];
  int g = blockIdx.x;
  int lo = gstart[g], hi = gstart[g + 1];
  int tid = threadIdx.x, wave = tid >> 6, lane = tid & 63;
  float a0 = 0.f, a1 = 0.f, a2 = 0.f, a3 = 0.f;
  for (int i = lo + wave; i < hi; i += 4) {
    ushort4 v = *(const ushort4*)(h + (size_t)i * D + lane * 4);
    a0 += bf2f(v.x); a1 += bf2f(v.y); a2 += bf2f(v.z); a3 += bf2f(v.w);
  }
  red[wave][lane * 4 + 0] = a0;
  red[wave][lane * 4 + 1] = a1;
  red[wave][lane * 4 + 2] = a2;
  red[wave][lane * 4 + 3] = a3;
  __syncthreads();
  float s = red[0][tid] + red[1][tid] + red[2][tid] + red[3][tid];
  float inv = (hi > lo) ? 1.0f / (float)(hi - lo) : 0.0f;
  float m = s * inv;                       // mean feature tid
  float4 wrow = *(const float4*)(linW + tid * 4);
  float p0 = m * wrow.x, p1 = m * wrow.y, p2 = m * wrow.z, p3 = m * wrow.w;
  for (int o = 32; o > 0; o >>= 1) {
    p0 += __shfl_down(p0, o, 64);
    p1 += __shfl_down(p1, o, 64);
    p2 += __shfl_down(p2, o, 64);
    p3 += __shfl_down(p3, o, 64);
  }
  if (lane == 0) {
    sred[wave][0] = p0; sred[wave][1] = p1;
    sred[wave][2] = p2; sred[wave][3] = p3;
  }
  __syncthreads();
  if (tid < 4)
    out[g * 4 + tid] = sred[0][tid] + sred[1][tid] + sred[2][tid] +
                       sred[3][tid] + linb[tid];
}

extern "C" void kernel_launch(void* const* d_in, const int* in_sizes, int n_in,
                              void* d_out, int out_size, void* d_ws, size_t ws_size,
                              hipStream_t stream) {
  const int*   x     = (const int*)d_in[0];
  const int*   ei    = (const int*)d_in[1];
  const int*   et    = (const int*)d_in[2];
  const int*   batch = (const int*)d_in[3];
  const float* table = (const float*)d_in[5];
  const float* W1    = (const float*)d_in[6];
  const float* root1 = (const float*)d_in[7];
  const float* b1    = (const float*)d_in[8];
  const float* W2    = (const float*)d_in[9];
  const float* root2 = (const float*)d_in[10];
  const float* b2    = (const float*)d_in[11];
  const float* linW  = (const float*)d_in[12];
  const float* linb  = (const float*)d_in[13];
  float* out = (float*)d_out;

  const int N = in_sizes[0];
  const int E = in_sizes[2];
  const int G = out_size / 4;
  const int VOC = in_sizes[5] / D;
  const int* src = ei;
  const int* dst = ei + E;
  const int RN = 3 * N;

  // ---- ws layout (~210 MB), page aliasing proven rounds 5-16 ----
  char* wsb = (char*)d_ws;
  size_t pg = (size_t)N * D * 2;
  unsigned short* P0 = (unsigned short*)wsb;
  unsigned short* P1 = (unsigned short*)(wsb + pg);
  unsigned short* P3 = (unsigned short*)(wsb + 3 * pg);
  unsigned short* wb = (unsigned short*)(wsb + 4 * pg);  // 2 layers x 4 mats
  int*   off    = (int*)(wb + 2 * 4 * 65536);
  int*   esx    = off + (RN + 1);       // L1 row ids (= x[src])
  int*   ess    = esx + E;              // L2 row ids (= src)
  int*   gstart = ess + E;
  unsigned short* tableb = P3;          // alias (dead before L2 agg writes P3)
  int* cur  = (int*)P0;                 // alias (dead before L1 agg writes P0)
  int* bsum = cur + RN;                 // alias

  const int nb = (RN + SB - 1) / SB;

  // ---- setup: one fused kernel for all independent prep ----
  int nbZero = (RN + 1023) / 1024;
  int nbBounds = (N + 255) / 256;
  int nbCvt = (VOC * D + 255) / 256;
  int g0 = nbZero, g1 = g0 + nbBounds, g2 = g1 + nbCvt, g3 = g2 + 1024;
  k_setup<<<g3 + 1024, 256, 0, stream>>>(cur, RN, batch, gstart, N, G,
      table, tableb, VOC * D, root1, W1, root2, W2, wb, g0, g1, g2, g3);

  k_count_i<<<(E + 255) / 256, 256, 0, stream>>>(dst, et, cur, E, N);
  k_scan1<<<nb, 256, 0, stream>>>(cur, bsum, RN);
  k_scan2<<<1, 256, 0, stream>>>(bsum, nb, off + RN);
  k_scan3<<<nb, 256, 0, stream>>>(cur, bsum, off, cur, RN);
  k_place2<<<(E + 255) / 256, 256, 0, stream>>>(src, dst, et, x, cur, esx, ess, E, N);

  const int gagg = (RN + 31) / 32;      // 8 ids/wave x 4 waves
  const int ggemm = (N + 127) / 128;

  // ---- layer 1 ----
  k_agg<<<gagg, 256, 0, stream>>>(tableb, esx, off, P0, RN);
  k_lgemm<<<ggemm, 512, 0, stream>>>(tableb, x, P0, wb, b1, P0, N, N);
  // ---- layer 2 ----
  k_agg<<<gagg, 256, 0, stream>>>(P0, ess, off, P1, RN);
  k_lgemm<<<ggemm, 512, 0, stream>>>(P0, nullptr, P1, wb + 4 * 65536, b2, P1, N, N);

  // ---- pool + head fused ----
  k_poolfinal<<<G, 256, 0, stream>>>(P1, gstart, linW, linb, out, G);
}

// Round 18
// 400.663 us; speedup vs baseline: 1.7477x; 1.0120x over previous
//
#include <hip/hip_runtime.h>

#define D 256
#define SB 1024
typedef __attribute__((ext_vector_type(8))) short short8;
typedef __attribute__((ext_vector_type(4))) float floatx4;

__device__ __forceinline__ unsigned short f2bf(float f) {
  unsigned int u = __float_as_uint(f);
  u = (u + 0x7FFF + ((u >> 16) & 1)) >> 16;   // RNE
  return (unsigned short)u;
}
__device__ __forceinline__ float bf2f(unsigned short h) {
  return __uint_as_float(((unsigned int)h) << 16);
}

// async global->LDS, 16B per lane; LDS dest = wave-uniform base + lane*16
__device__ __forceinline__ void glds16(const void* g, void* l) {
  __builtin_amdgcn_global_load_lds(
      (const __attribute__((address_space(1))) unsigned int*)g,
      (__attribute__((address_space(3))) unsigned int*)l, 16, 0, 0);
}

// ---------------- fused independent setup: zero | bounds | cvt | cvt_w x2 --
__global__ __launch_bounds__(256) void k_setup(
    int* __restrict__ cur, int RN,
    const int* __restrict__ batch, int* __restrict__ gstart, int N, int G,
    const float* __restrict__ table, unsigned short* __restrict__ tableb, int TN,
    const float* __restrict__ root1, const float* __restrict__ W1,
    const float* __restrict__ root2, const float* __restrict__ W2,
    unsigned short* __restrict__ wb,
    int g0, int g1, int g2, int g3) {
  int b = blockIdx.x, t = threadIdx.x;
  if (b < g0) {                       // zero cur, int4 per thread
    int i = b * 1024 + t * 4;
#pragma unroll
    for (int j = 0; j < 4; j++) if (i + j < RN) cur[i + j] = 0;
  } else if (b < g1) {                // graph bounds
    int i = (b - g0) * 256 + t;
    if (i >= N) return;
    int bb = batch[i];
    if (i == 0) { for (int g = 0; g <= bb; g++) gstart[g] = 0; }
    else { int pb = batch[i - 1]; for (int g = pb + 1; g <= bb; g++) gstart[g] = i; }
    if (i == N - 1) { for (int g = bb + 1; g <= G; g++) gstart[g] = N; }
  } else if (b < g2) {                // table fp32 -> bf16
    int i = (b - g1) * 256 + t;
    if (i < TN) tableb[i] = f2bf(table[i]);
  } else {                            // weights -> bf16 transposed [mat][n][k]
    int layer = (b < g3) ? 0 : 1;
    int idx = ((b - (layer ? g3 : g2)) * 256 + t);   // 0 .. 4*65536-1
    int mat = idx >> 16, rem = idx & 65535;
    int n = rem >> 8, k = rem & 255;
    const float* root = layer ? root2 : root1;
    const float* W = layer ? W2 : W1;
    const float* s = (mat == 0) ? root : (W + (size_t)(mat - 1) * 65536);
    wb[(size_t)layer * 4 * 65536 + idx] = f2bf(s[k * 256 + n]);
  }
}

// ---------------- per-(relation,node) in-edge counts ----------------
__global__ __launch_bounds__(256) void k_count_i(const int* __restrict__ dst,
    const int* __restrict__ et, int* __restrict__ cnt, int E, int N) {
  int e = blockIdx.x * 256 + threadIdx.x;
  if (e >= E) return;
  atomicAdd(&cnt[et[e] * N + dst[e]], 1);
}

// ---------------- 3-kernel scan chain (proven r11/r14) ----------------
__global__ __launch_bounds__(256) void k_scan1(const int* __restrict__ in,
    int* __restrict__ bsum, int n) {
  __shared__ int s[256];
  int base = blockIdx.x * SB, t = threadIdx.x;
  int a = 0;
#pragma unroll
  for (int j = 0; j < 4; j++) { int i = base + t * 4 + j; if (i < n) a += in[i]; }
  s[t] = a; __syncthreads();
  for (int o = 128; o > 0; o >>= 1) { if (t < o) s[t] += s[t + o]; __syncthreads(); }
  if (t == 0) bsum[blockIdx.x] = s[0];
}

__global__ __launch_bounds__(256) void k_scan2(int* __restrict__ bsum, int nb,
    int* __restrict__ total_out) {
  __shared__ int s[256];
  int t = threadIdx.x;
  int v[4]; int a = 0;
#pragma unroll
  for (int j = 0; j < 4; j++) {
    int i = t * 4 + j;
    v[j] = (i < nb) ? bsum[i] : 0;
    a += v[j];
  }
  s[t] = a; __syncthreads();
  for (int o = 1; o < 256; o <<= 1) {
    int x_ = (t >= o) ? s[t - o] : 0;
    __syncthreads();
    s[t] += x_;
    __syncthreads();
  }
  int excl = (t > 0) ? s[t - 1] : 0;
#pragma unroll
  for (int j = 0; j < 4; j++) {
    int i = t * 4 + j;
    if (i < nb) { bsum[i] = excl; excl += v[j]; }
  }
  if (t == 255) *total_out = s[255];
}

__global__ __launch_bounds__(256) void k_scan3(const int* __restrict__ in,
    const int* __restrict__ bsum, int* __restrict__ off, int* __restrict__ cur,
    int n) {
  __shared__ int s[256];
  int base = blockIdx.x * SB, t = threadIdx.x;
  int v[4]; int a = 0;
#pragma unroll
  for (int j = 0; j < 4; j++) {
    int i = base + t * 4 + j;
    v[j] = (i < n) ? in[i] : 0;
    a += v[j];
  }
  s[t] = a; __syncthreads();
  for (int o = 1; o < 256; o <<= 1) {
    int x_ = (t >= o) ? s[t - o] : 0;
    __syncthreads();
    s[t] += x_;
    __syncthreads();
  }
  int excl = (t > 0 ? s[t - 1] : 0) + bsum[blockIdx.x];
#pragma unroll
  for (int j = 0; j < 4; j++) {
    int i = base + t * 4 + j;
    if (i < n) { off[i] = excl; cur[i] = excl; excl += v[j]; }
  }
}

// CSR placement: esx[pos] = x[src] (L1 row id), ess[pos] = src (L2 row id)
__global__ __launch_bounds__(256) void k_place2(const int* __restrict__ src,
    const int* __restrict__ dst, const int* __restrict__ et,
    const int* __restrict__ x, int* __restrict__ cur,
    int* __restrict__ esx, int* __restrict__ ess, int E, int N) {
  int e = blockIdx.x * 256 + threadIdx.x;
  if (e >= E) return;
  int s = src[e];
  int pos = atomicAdd(&cur[et[e] * N + dst[e]], 1);
  esx[pos] = x[s];
  ess[pos] = s;
}

// ---------------- relation aggregation, 8 ids per wave (ILP batch) --------
__global__ __launch_bounds__(256) void k_agg(const unsigned short* __restrict__ h,
    const int* __restrict__ rows, const int* __restrict__ off,
    unsigned short* __restrict__ out, int RN) {
  const int wave = threadIdx.x >> 6, lane = threadIdx.x & 63;
  const int base = (blockIdx.x * 4 + wave) * 8;
  if (base >= RN) return;

  int lo[8], hi[8];
#pragma unroll
  for (int j = 0; j < 8; j++) {
    int id = base + j;
    lo[j] = (id < RN) ? off[id] : 0;
    hi[j] = (id < RN) ? off[id + 1] : 0;
  }

  int r0[8];
#pragma unroll
  for (int j = 0; j < 8; j++)
    r0[j] = (hi[j] > lo[j]) ? rows[lo[j]] : 0;

  ushort4 v0[8];
#pragma unroll
  for (int j = 0; j < 8; j++)
    v0[j] = (hi[j] > lo[j])
        ? *(const ushort4*)(h + (size_t)r0[j] * D + lane * 4)
        : make_ushort4(0, 0, 0, 0);

  float a[8][4];
#pragma unroll
  for (int j = 0; j < 8; j++) {
    a[j][0] = bf2f(v0[j].x); a[j][1] = bf2f(v0[j].y);
    a[j][2] = bf2f(v0[j].z); a[j][3] = bf2f(v0[j].w);
  }

#pragma unroll
  for (int j = 0; j < 8; j++) {
    for (int p = lo[j] + 1; p < hi[j]; ++p) {
      int r = rows[p];
      ushort4 v = *(const ushort4*)(h + (size_t)r * D + lane * 4);
      a[j][0] += bf2f(v.x); a[j][1] += bf2f(v.y);
      a[j][2] += bf2f(v.z); a[j][3] += bf2f(v.w);
    }
  }

#pragma unroll
  for (int j = 0; j < 8; j++) {
    int id = base + j;
    if (id >= RN) continue;
    int c = hi[j] - lo[j];
    float inv = 1.0f / (float)(c > 0 ? c : 1);
    ushort4 o;
    o.x = f2bf(a[j][0] * inv); o.y = f2bf(a[j][1] * inv);
    o.z = f2bf(a[j][2] * inv); o.w = f2bf(a[j][3] * inv);
    *(ushort4*)(out + (size_t)id * D + lane * 4) = o;
  }
}

// ---------------- fused K=1024 bf16 MFMA GEMM, glds + BK=64 ---------------
// r17 (glds, BK=32): 83.3 us, MfmaUtil 25%. Remaining stall = 32 vmcnt(0)
// drains at the staging barrier. BK=64 halves the drain count; with glds
// there is NO register staging, so (unlike r9's spill disaster) the cost is
// only LDS 24->48 KB — and the grid (782 blocks / 256 CU ~ 3/CU) already
// caps occupancy at 3 blocks/CU, which 48 KB still allows. 16 barrier-pairs
// of {6 glds -> drain -> 2x(frag reads + 16 MFMA)}.
__global__ __launch_bounds__(512) void k_lgemm(
    const unsigned short* __restrict__ Aroot, const int* __restrict__ gidx,
    const unsigned short* agg, const unsigned short* __restrict__ wb,
    const float* __restrict__ bias, unsigned short* Cout, int M, int N) {
  __shared__ unsigned short AsU[2][128 * 32];    // 2 x 8 KB  [row][k]
  __shared__ unsigned short BsU[2][256 * 32];    // 2 x 16 KB [n][k]
  const int tid = threadIdx.x;
  const int w = tid >> 6, lane = tid & 63;
  const int wr = w >> 2, wc = w & 3;             // wave grid 2x4
  const int i0 = blockIdx.x * 128;
  const int ml = lane & 15, q = lane >> 4;

  // A staging: wave w stages rows w*16..w*16+15 (1 KB / instr).
  const int arow = w * 16 + (lane >> 2);
  const int achunk = lane & 3;
  int ra = i0 + arow;
  int rac = (ra < M) ? ra : (M - 1);
  const int rowA0 = gidx ? gidx[rac] : rac;
  const unsigned short* a0base[4];
  a0base[0] = Aroot + (size_t)rowA0 * D + achunk * 8;
#pragma unroll
  for (int r = 0; r < 3; r++)
    a0base[r + 1] = agg + ((size_t)r * N + rac) * D + achunk * 8;

  // B staging: wave w stages rows w*32..w*32+31 (2 instrs of 1 KB).
  const int brow = w * 32 + (lane >> 2);
  const int bchunk = lane & 3;
  const size_t bofs = (size_t)brow * D + bchunk * 8;

  floatx4 acc[4][4];
#pragma unroll
  for (int i = 0; i < 4; i++)
#pragma unroll
    for (int j = 0; j < 4; j++) acc[i][j] = (floatx4){0.f, 0.f, 0.f, 0.f};

  unsigned short* aldst[2] = {&AsU[0][w * 512], &AsU[1][w * 512]};
  unsigned short* bldst0[2] = {&BsU[0][w * 1024], &BsU[1][w * 1024]};
  unsigned short* bldst1[2] = {&BsU[0][w * 1024 + 512], &BsU[1][w * 1024 + 512]};

  for (int step = 0; step < 16; ++step) {
    __syncthreads();                    // previous step's LDS reads done
#pragma unroll
    for (int h = 0; h < 2; h++) {
      const int kabs = step * 64 + h * 32;
      const int seg = kabs >> 8, kloc = kabs & 255;
      glds16(a0base[seg] + kloc, aldst[h]);
      const unsigned short* bb = wb + (size_t)seg * 65536 + bofs + kloc;
      glds16(bb, bldst0[h]);
      glds16(bb + 16 * D, bldst1[h]);
    }
    __syncthreads();                    // vmcnt drained -> LDS populated

#pragma unroll
    for (int h = 0; h < 2; h++) {
      short8 aF[4], bF[4];
#pragma unroll
      for (int mi = 0; mi < 4; mi++)
        aF[mi] = *(const short8*)&AsU[h][(wr * 64 + mi * 16 + ml) * 32 + q * 8];
#pragma unroll
      for (int ni = 0; ni < 4; ni++)
        bF[ni] = *(const short8*)&BsU[h][(wc * 64 + ni * 16 + ml) * 32 + q * 8];
#pragma unroll
      for (int mi = 0; mi < 4; mi++)
#pragma unroll
        for (int ni = 0; ni < 4; ni++)
          acc[mi][ni] = __builtin_amdgcn_mfma_f32_16x16x32_bf16(
              aF[mi], bF[ni], acc[mi][ni], 0, 0, 0);
    }
  }

  // per-block read-before-write over input pages: reads precede C writes
  __syncthreads();

  // epilogue: bias + ReLU + bf16; C/D layout col=lane&15, row=q*4+reg
  float bv[4];
#pragma unroll
  for (int ni = 0; ni < 4; ni++) bv[ni] = bias[wc * 64 + ni * 16 + ml];
#pragma unroll
  for (int mi = 0; mi < 4; mi++) {
#pragma unroll
    for (int ni = 0; ni < 4; ni++) {
      int col = wc * 64 + ni * 16 + ml;
#pragma unroll
      for (int j = 0; j < 4; j++) {
        int row = i0 + wr * 64 + mi * 16 + q * 4 + j;
        if (row < M) {
          float v = fmaxf(acc[mi][ni][j] + bv[ni], 0.f);
          Cout[(size_t)row * D + col] = f2bf(v);
        }
      }
    }
  }
}

// ---------------- fused graph mean-pool + linear head ----------------
__global__ __launch_bounds__(256) void k_poolfinal(
    const unsigned short* __restrict__ h, const int* __restrict__ gstart,
    const float* __restrict__ linW, const float* __restrict__ linb,
    float* __restrict__ out, int G) {
  __shared__ float red[4][D];
  __shared__ float sred[4][4];
  int g = blockIdx.x;
  int lo = gstart[g], hi = gstart[g + 1];
  int tid = threadIdx.x, wave = tid >> 6, lane = tid & 63;
  float a0 = 0.f, a1 = 0.f, a2 = 0.f, a3 = 0.f;
  for (int i = lo + wave; i < hi; i += 4) {
    ushort4 v = *(const ushort4*)(h + (size_t)i * D + lane * 4);
    a0 += bf2f(v.x); a1 += bf2f(v.y); a2 += bf2f(v.z); a3 += bf2f(v.w);
  }
  red[wave][lane * 4 + 0] = a0;
  red[wave][lane * 4 + 1] = a1;
  red[wave][lane * 4 + 2] = a2;
  red[wave][lane * 4 + 3] = a3;
  __syncthreads();
  float s = red[0][tid] + red[1][tid] + red[2][tid] + red[3][tid];
  float inv = (hi > lo) ? 1.0f / (float)(hi - lo) : 0.0f;
  float m = s * inv;                       // mean feature tid
  float4 wrow = *(const float4*)(linW + tid * 4);
  float p0 = m * wrow.x, p1 = m * wrow.y, p2 = m * wrow.z, p3 = m * wrow.w;
  for (int o = 32; o > 0; o >>= 1) {
    p0 += __shfl_down(p0, o, 64);
    p1 += __shfl_down(p1, o, 64);
    p2 += __shfl_down(p2, o, 64);
    p3 += __shfl_down(p3, o, 64);
  }
  if (lane == 0) {
    sred[wave][0] = p0; sred[wave][1] = p1;
    sred[wave][2] = p2; sred[wave][3] = p3;
  }
  __syncthreads();
  if (tid < 4)
    out[g * 4 + tid] = sred[0][tid] + sred[1][tid] + sred[2][tid] +
                       sred[3][tid] + linb[tid];
}

extern "C" void kernel_launch(void* const* d_in, const int* in_sizes, int n_in,
                              void* d_out, int out_size, void* d_ws, size_t ws_size,
                              hipStream_t stream) {
  const int*   x     = (const int*)d_in[0];
  const int*   ei    = (const int*)d_in[1];
  const int*   et    = (const int*)d_in[2];
  const int*   batch = (const int*)d_in[3];
  const float* table = (const float*)d_in[5];
  const float* W1    = (const float*)d_in[6];
  const float* root1 = (const float*)d_in[7];
  const float* b1    = (const float*)d_in[8];
  const float* W2    = (const float*)d_in[9];
  const float* root2 = (const float*)d_in[10];
  const float* b2    = (const float*)d_in[11];
  const float* linW  = (const float*)d_in[12];
  const float* linb  = (const float*)d_in[13];
  float* out = (float*)d_out;

  const int N = in_sizes[0];
  const int E = in_sizes[2];
  const int G = out_size / 4;
  const int VOC = in_sizes[5] / D;
  const int* src = ei;
  const int* dst = ei + E;
  const int RN = 3 * N;

  // ---- ws layout (~210 MB), page aliasing proven rounds 5-17 ----
  char* wsb = (char*)d_ws;
  size_t pg = (size_t)N * D * 2;
  unsigned short* P0 = (unsigned short*)wsb;
  unsigned short* P1 = (unsigned short*)(wsb + pg);
  unsigned short* P3 = (unsigned short*)(wsb + 3 * pg);
  unsigned short* wb = (unsigned short*)(wsb + 4 * pg);  // 2 layers x 4 mats
  int*   off    = (int*)(wb + 2 * 4 * 65536);
  int*   esx    = off + (RN + 1);       // L1 row ids (= x[src])
  int*   ess    = esx + E;              // L2 row ids (= src)
  int*   gstart = ess + E;
  unsigned short* tableb = P3;          // alias (dead before L2 agg writes P3)
  int* cur  = (int*)P0;                 // alias (dead before L1 agg writes P0)
  int* bsum = cur + RN;                 // alias

  const int nb = (RN + SB - 1) / SB;

  // ---- setup: one fused kernel for all independent prep ----
  int nbZero = (RN + 1023) / 1024;
  int nbBounds = (N + 255) / 256;
  int nbCvt = (VOC * D + 255) / 256;
  int g0 = nbZero, g1 = g0 + nbBounds, g2 = g1 + nbCvt, g3 = g2 + 1024;
  k_setup<<<g3 + 1024, 256, 0, stream>>>(cur, RN, batch, gstart, N, G,
      table, tableb, VOC * D, root1, W1, root2, W2, wb, g0, g1, g2, g3);

  k_count_i<<<(E + 255) / 256, 256, 0, stream>>>(dst, et, cur, E, N);
  k_scan1<<<nb, 256, 0, stream>>>(cur, bsum, RN);
  k_scan2<<<1, 256, 0, stream>>>(bsum, nb, off + RN);
  k_scan3<<<nb, 256, 0, stream>>>(cur, bsum, off, cur, RN);
  k_place2<<<(E + 255) / 256, 256, 0, stream>>>(src, dst, et, x, cur, esx, ess, E, N);

  const int gagg = (RN + 31) / 32;      // 8 ids/wave x 4 waves
  const int ggemm = (N + 127) / 128;

  // ---- layer 1 ----
  k_agg<<<gagg, 256, 0, stream>>>(tableb, esx, off, P0, RN);
  k_lgemm<<<ggemm, 512, 0, stream>>>(tableb, x, P0, wb, b1, P0, N, N);
  // ---- layer 2 ----
  k_agg<<<gagg, 256, 0, stream>>>(P0, ess, off, P1, RN);
  k_lgemm<<<ggemm, 512, 0, stream>>>(P0, nullptr, P1, wb + 4 * 65536, b2, P1, N, N);

  // ---- pool + head fused ----
  k_poolfinal<<<G, 256, 0, stream>>>(P1, gstart, linW, linb, out, G);
}